// Round 15
// baseline (324.747 us; speedup 1.0000x reference)
//
#include <hip/hip_runtime.h>
#include <stdint.h>

// Calibration-histogram kernel for MI355X (round 15).
// probs: (1,2,4096,4096) f32, labels: (1,1,4096,4096) i32.
// Outputs (flat, 90 f32): count0[15], csum0[15], asum0[15], count1[15], csum1[15], asum1[15].
//
// Round-14 post-mortem: register accumulators finally clean (VGPR 32, no
// scratch) but VALU duty only 31% -> latency-bound: 2 loads then ~110
// wave-cyc compute per iter doesn't cover ~1-2K cyc memory latency.
// Fix: UNROLL x4 -- issue 8 independent dwordx4 loads back-to-back, then
// 16 updates (~880 wave-cyc VALU) -> even 2-3 waves/SIMD saturate VALU.
// Channel-split blocks (15 named u32 accumulators, low VGPR pressure).
// Packed u32 per bin: [31:14] csum (conf*2048 trunc) | [13:7] asum | [6:0] count.
// Grid 4096 (2048/channel): each thread exactly 8 vec4 -> count<=32;
// after shfl_xor(32) pair-reduce <=64 < 128; csum <= 64*2048 = 131072 < 2^18.
// NO __launch_bounds__ 2nd arg (r12/r13 proved it forces VGPR collapse+spill).

#define NBINS 15

__global__ void zero_out_kernel(float* out, int n) {
    int i = blockIdx.x * blockDim.x + threadIdx.x;
    if (i < n) out[i] = 0.0f;
}

// v/bin for one element. (lab ^ flip) & 1 == (lab == ch) since lab in {0,1}.
#define PACK(c_, lab_)                                                \
    {                                                                 \
        float _c = (c_);                                              \
        bin = (int)fminf(_c * 15.0f, 14.0f);                          \
        unsigned _cf = (unsigned)(_c * 2048.0f);                      \
        v = (_cf << 14) | ((unsigned)(((lab_) ^ flip) & 1) << 7) | 1u;\
        v = (_c > 0.0f) ? v : 0u;                                     \
    }

#define SEL_ALL                                                       \
    s0  += (bin == 0 ) ? v : 0u;  s1  += (bin == 1 ) ? v : 0u;        \
    s2  += (bin == 2 ) ? v : 0u;  s3  += (bin == 3 ) ? v : 0u;        \
    s4  += (bin == 4 ) ? v : 0u;  s5  += (bin == 5 ) ? v : 0u;        \
    s6  += (bin == 6 ) ? v : 0u;  s7  += (bin == 7 ) ? v : 0u;        \
    s8  += (bin == 8 ) ? v : 0u;  s9  += (bin == 9 ) ? v : 0u;        \
    s10 += (bin == 10) ? v : 0u;  s11 += (bin == 11) ? v : 0u;        \
    s12 += (bin == 12) ? v : 0u;  s13 += (bin == 13) ? v : 0u;        \
    s14 += (bin == 14) ? v : 0u;

#define UPD4(a_, l_)                                                  \
    PACK(a_.x, l_.x) SEL_ALL                                          \
    PACK(a_.y, l_.y) SEL_ALL                                          \
    PACK(a_.z, l_.z) SEL_ALL                                          \
    PACK(a_.w, l_.w) SEL_ALL

#define PR(x) x += (unsigned)__shfl_xor((int)(x), 32);

__global__ __launch_bounds__(256) void calib_hist_kernel(
        const float* __restrict__ probs, const int* __restrict__ labels,
        float* __restrict__ out, int npix) {
    // Block -> (channel, pair index). Pairs (same p, ch0/ch1) are 8 apart in
    // blockIdx -> same XCD slot under round-robin -> labels 2nd read L2-hits.
    int g  = blockIdx.x;
    int ch = (g >> 3) & 1;
    int p  = ((g >> 4) << 3) | (g & 7);          // 0 .. gridDim/2 - 1
    unsigned flip = (unsigned)(ch ^ 1);

    unsigned s0=0,s1=0,s2=0,s3=0,s4=0,s5=0,s6=0,s7=0,s8=0,s9=0,s10=0,s11=0,s12=0,s13=0,s14=0;

    const float4* pc = (const float4*)(probs + (size_t)ch * npix);
    const int4*   lb = (const int4*)labels;
    int nvec = npix >> 2;
    int nth  = (gridDim.x >> 1) << 8;            // threads per channel
    int tid  = threadIdx.x;
    int i    = p * 256 + tid;

    // Unrolled-by-4 main loop: 8 independent loads issued together, then
    // 16 updates (~880 wave-cyc VALU) -> deep ILP hides memory latency.
    for (; i + 3 * nth < nvec; i += 4 * nth) {
        float4 a0 = pc[i];
        float4 a1 = pc[i + nth];
        float4 a2 = pc[i + 2 * nth];
        float4 a3 = pc[i + 3 * nth];
        int4   l0 = lb[i];
        int4   l1 = lb[i + nth];
        int4   l2 = lb[i + 2 * nth];
        int4   l3 = lb[i + 3 * nth];
        unsigned v; int bin;
        UPD4(a0, l0)
        UPD4(a1, l1)
        UPD4(a2, l2)
        UPD4(a3, l3)
    }
    for (; i < nvec; i += nth) {                 // tail (none at 4096^2)
        float4 a = pc[i];
        int4   l = lb[i];
        unsigned v; int bin;
        UPD4(a, l)
    }

    // Pair-reduce lane^32 in registers (count<=32 -> <=64 < 128: no carry).
    PR(s0) PR(s1) PR(s2) PR(s3) PR(s4) PR(s5) PR(s6) PR(s7)
    PR(s8) PR(s9) PR(s10) PR(s11) PR(s12) PR(s13) PR(s14)

    // Lanes <32 of each of 4 waves write hist[e][col], col = wid*32+lane.
    // bank(word = e*128+col) = col&31 = lane -> conflict-free stores.
    __shared__ unsigned hist[15 * 128];   // 7.5 KB
    int lane = tid & 63, wid = tid >> 6;
    if (lane < 32) {
        int col = wid * 32 + lane;
        hist[ 0*128+col]=s0;  hist[ 1*128+col]=s1;  hist[ 2*128+col]=s2;
        hist[ 3*128+col]=s3;  hist[ 4*128+col]=s4;  hist[ 5*128+col]=s5;
        hist[ 6*128+col]=s6;  hist[ 7*128+col]=s7;  hist[ 8*128+col]=s8;
        hist[ 9*128+col]=s9;  hist[10*128+col]=s10; hist[11*128+col]=s11;
        hist[12*128+col]=s12; hist[13*128+col]=s13; hist[14*128+col]=s14;
    }
    __syncthreads();

    // Merge: thread h<120 owns bin e=h>>3 and 16-col chunk (h&7)*16, rotated
    // by h. Unpack BEFORE summing. 8-lane shfl reduce, one atomic triple/bin.
    if (tid < 120) {
        int e = tid >> 3;                  // 0..14
        unsigned cnt = 0, asum = 0, csum = 0;
        int chunk = (tid & 7) * 16;
        #pragma unroll
        for (int j = 0; j < 16; ++j) {
            int col = chunk + ((j + tid) & 15);
            unsigned x = hist[e * 128 + col];
            cnt  += x & 0x7Fu;
            asum += (x >> 7) & 0x7Fu;
            csum += x >> 14;
        }
        cnt  += __shfl_xor(cnt, 1); asum += __shfl_xor(asum, 1); csum += __shfl_xor(csum, 1);
        cnt  += __shfl_xor(cnt, 2); asum += __shfl_xor(asum, 2); csum += __shfl_xor(csum, 2);
        cnt  += __shfl_xor(cnt, 4); asum += __shfl_xor(asum, 4); csum += __shfl_xor(csum, 4);
        if ((tid & 7) == 0) {
            float* obase = out + ch * 45;
            atomicAdd(obase + e,             (float)cnt);
            atomicAdd(obase + NBINS + e,     (float)csum * (1.0f / 2048.0f));
            atomicAdd(obase + 2 * NBINS + e, (float)asum);
        }
    }
}

extern "C" void kernel_launch(void* const* d_in, const int* in_sizes, int n_in,
                              void* d_out, int out_size, void* d_ws, size_t ws_size,
                              hipStream_t stream) {
    const float* probs  = (const float*)d_in[0];
    const int*   labels = (const int*)d_in[1];
    float*       out    = (float*)d_out;
    int npix = in_sizes[1];  // 4096*4096 pixels; probs has 2*npix elements

    zero_out_kernel<<<(out_size + 127) / 128, 128, 0, stream>>>(out, out_size);

    // 2048 blocks per channel: each thread handles EXACTLY 8 vec4 at 4096^2
    // (4194304 / (2048*256) = 8) -> no tail, count<=32 (carry-safe).
    int nvec = npix >> 2;
    int blkch = (nvec + 256 * 8 - 1) / (256 * 8);
    if (blkch < 1) blkch = 1;
    calib_hist_kernel<<<2 * blkch, 256, 0, stream>>>(probs, labels, out, npix);
}